// Round 6
// baseline (243.891 us; speedup 1.0000x reference)
//
#include <hip/hip_runtime.h>
#include <math.h>

typedef short  short8  __attribute__((ext_vector_type(8)));
typedef float  floatx4 __attribute__((ext_vector_type(4)));

#define NROWS 16384
#define KC    2048
#define DIM   512
#define MB    32      // rows per k_main block

// d_out element offsets (all float32): loss, q[8388608], perplexity, idx[16384]
#define OUT_Q_OFF    1
#define OUT_P_OFF    (1 + 8388608)
#define OUT_IDX_OFF  (1 + 8388608 + 1)

// ws byte offsets
#define WS_COUNTS 0        // int[2048]   (zeroed in k_prep)
#define WS_LOSS   8192     // float       (zeroed in k_prep)
#define WS_W2D    8448     // double[2048]
#define WS_W2F    24832    // float[2048]
#define WS_WB     33024    // ushort[(2048+64)*512] bf16 codebook, FRAGMENT-ORDERED (+64KB ring pad)

__device__ __forceinline__ unsigned short f2bf(float f) {
  union { float f; unsigned int u; } v; v.f = f;
  unsigned int u = v.u;
  return (unsigned short)((u + 0x7fffu + ((u >> 16) & 1u)) >> 16);
}

// monotone pack: fp32 score -> ascending uint, low 11 bits replaced by code
__device__ __forceinline__ unsigned int packsc(float s, int code) {
  union { float f; unsigned int u; } v; v.f = s;
  unsigned int u = v.u;
  u = (u & 0x80000000u) ? ~u : (u | 0x80000000u);
  return (u & 0xFFFFF800u) | (unsigned int)code;
}

__device__ __forceinline__ void ins3(unsigned int* t, unsigned int v) {
  if (v < t[2]) {
    t[2] = v;
    if (t[2] < t[1]) { unsigned int tmp = t[1]; t[1] = t[2]; t[2] = tmp; }
    if (t[1] < t[0]) { unsigned int tmp = t[0]; t[0] = t[1]; t[1] = tmp; }
  }
}

// ---------------- k_prep: fused (counts/loss zero) + ||W||^2 + W-reorder
// blocks [0,512):    ||W_k||^2 fp64+fp32, 4 codes per block (+ counts zeroing on blocks 0..8)
// blocks [512,1024): W -> bf16 fragment-ordered Wb (4 fragments per block)
__global__ __launch_bounds__(256) void k_prep(
    const float* __restrict__ W,
    double* __restrict__ w2d, float* __restrict__ w2f,
    unsigned short* __restrict__ Wb,
    int* __restrict__ counts, float* __restrict__ loss_acc)
{
  const int bid = blockIdx.x;
  const int tid = threadIdx.x;

  if (bid < 512) {
    if (bid < 8) counts[bid * 256 + tid] = 0;
    if (bid == 8 && tid == 0) *loss_acc = 0.0f;

    int wave = tid >> 6;
    int lane = tid & 63;
    int k = bid * 4 + wave;
    const float4* row = (const float4*)(W + (size_t)k * DIM);
    float4 a = row[lane];
    float4 b = row[lane + 64];
    double acc = 0.0;
    acc += (double)a.x*a.x + (double)a.y*a.y + (double)a.z*a.z + (double)a.w*a.w;
    acc += (double)b.x*b.x + (double)b.y*b.y + (double)b.z*b.z + (double)b.w*b.w;
    for (int o = 32; o > 0; o >>= 1) acc += __shfl_down(acc, o);
    if (lane == 0) { w2d[k] = acc; w2f[k] = (float)acc; }
  } else {
    int gid  = (bid - 512) * 256 + tid;           // 131072 total
    int lane = gid & 63;
    int f    = gid >> 6;                           // 0..2047
    int c16  = f >> 4, ks = f & 15;
    int l15  = lane & 15, q = lane >> 4;
    const float* src = W + (size_t)(c16 * 16 + l15) * DIM + ks * 32 + q * 8;
    float4 a = *(const float4*)src;
    float4 b = *(const float4*)(src + 4);
    short8 v;
    v[0] = (short)f2bf(a.x); v[1] = (short)f2bf(a.y);
    v[2] = (short)f2bf(a.z); v[3] = (short)f2bf(a.w);
    v[4] = (short)f2bf(b.x); v[5] = (short)f2bf(b.y);
    v[6] = (short)f2bf(b.z); v[7] = (short)f2bf(b.w);
    *(short8*)(Wb + (size_t)f * 512 + lane * 8) = v;
  }
}

// ---------------- k_main: monolith (A..E). Structure lessons (measured):
//  - D/E stay fused (R2: standalone D/E ~100us exposed latency vs ~20us fused).
//  - Phase A stays direct per-lane strided loads (R1/R3: staging costs +25us).
//  - Phase B waves keep contiguous disjoint 512KB streams (R5: 16KB wave-
//    interleave cost +27us; L2 already absorbs cross-block Wb redundancy).
//  - Ring deepened 8->16: Phase B issues 1KB per ~580cyc/wave at ring=8 =>
//    vmcnt-stall (MLP-starved). 16KB in flight halves the exposed latency.
__global__ __launch_bounds__(256, 2) void k_main(
    const float* __restrict__ x, const float* __restrict__ W,
    const unsigned short* __restrict__ Wb,
    const float* __restrict__ w2f, const double* __restrict__ w2d,
    int* __restrict__ counts, float* __restrict__ out,
    float* __restrict__ loss_acc)
{
  // Phase C merge buffers, padded strides (candU 193, ps8 65): conflict-light
  // (R5 measured: SQ_LDS_BANK_CONFLICT 1.85M -> 248K)
  __shared__ __align__(16) char smem[33024];
  __shared__ double sc8[MB][8];
  __shared__ int    top8i[MB][8];
  __shared__ int4   idx3s[MB];
  __shared__ float  lred[4];

  unsigned int* candU = (unsigned int*)smem;             // [32 * 193]
  unsigned int* ps8   = (unsigned int*)(smem + 24704);   // [32 * 65]

  const int tid  = threadIdx.x;
  const int w    = tid >> 6;          // wave id: owns codes [w*512, w*512+512)
  const int lane = tid & 63;
  const int q    = lane >> 4;
  const int l15  = lane & 15;
  const int n0   = blockIdx.x * MB;
  const int b    = n0 >> 8;
  const int t0   = n0 & 255;

  // ---- Phase A: 32 rows -> bf16 A-fragments in registers (2 rowsets x 16 ksteps)
  short8 af[2][16];
  {
    const float* x0 = x + (size_t)b * DIM * 256 + t0 + l15;
    #pragma unroll
    for (int rs = 0; rs < 2; ++rs)
      #pragma unroll
      for (int s = 0; s < 16; ++s) {
        short8 v;
        #pragma unroll
        for (int j = 0; j < 8; ++j) {
          int d = s * 32 + q * 8 + j;
          v[j] = (short)f2bf(x0[(size_t)d * 256 + rs * 16]);
        }
        af[rs][s] = v;
      }
  }

  unsigned int ts[2][4][3];   // packed top-3 per (rowset, acc-reg)
  #pragma unroll
  for (int rs = 0; rs < 2; ++rs)
    #pragma unroll
    for (int i = 0; i < 4; ++i)
      #pragma unroll
      for (int j = 0; j < 3; ++j) ts[rs][i][j] = 0xFFFFFFFFu;

  // ---- Phase B: barrier-free GEMM. Each wave streams its contiguous 512 KB of
  //      fragment-ordered Wb through a 16-deep register ring (16KB in flight).
  //      Prefetch distance 16; max touched fragment = 3*512 + 511 + 16 = 2063
  //      < 2112 (Wb pad) => clamp-free.
  {
    const unsigned short* base = Wb + (size_t)(w * 512) * 512 + lane * 8;
    short8 ring[16];
    #pragma unroll
    for (int p = 0; p < 16; ++p)
      ring[p] = *(const short8*)(base + (size_t)p * 512);

    for (int ct = 0; ct < 32; ++ct) {
      floatx4 acc0 = {0.f, 0.f, 0.f, 0.f};
      floatx4 acc1 = {0.f, 0.f, 0.f, 0.f};
      #pragma unroll
      for (int ks = 0; ks < 16; ++ks) {
        int it = ct * 16 + ks;
        short8 bfr = ring[ks];
        ring[ks] = *(const short8*)(base + (size_t)(it + 16) * 512);
        acc0 = __builtin_amdgcn_mfma_f32_16x16x32_bf16(af[0][ks], bfr, acc0, 0, 0, 0);
        acc1 = __builtin_amdgcn_mfma_f32_16x16x32_bf16(af[1][ks], bfr, acc1, 0, 0, 0);
      }
      int code = (w * 32 + ct) * 16 + l15;
      float w2 = w2f[code];
      #pragma unroll
      for (int i = 0; i < 4; ++i) {
        ins3(ts[0][i], packsc(fmaf(-2.0f, acc0[i], w2), code));
        ins3(ts[1][i], packsc(fmaf(-2.0f, acc1[i], w2), code));
      }
    }
  }

  // ---- Phase C: dump packed candidates, two-stage merge -> top-8 per row
  #pragma unroll
  for (int rs = 0; rs < 2; ++rs)
    #pragma unroll
    for (int i = 0; i < 4; ++i) {
      int row = rs * 16 + q * 4 + i;
      #pragma unroll
      for (int j = 0; j < 3; ++j)
        candU[row * 193 + w * 48 + l15 * 3 + j] = ts[rs][i][j];
    }
  __syncthreads();

  {
    int row = tid >> 3, sl = tid & 7;
    unsigned int s8[8];
    #pragma unroll
    for (int k = 0; k < 8; ++k) s8[k] = 0xFFFFFFFFu;
    for (int e = 0; e < 24; ++e) {
      unsigned int v = candU[row * 193 + sl * 24 + e];
      if (v < s8[7]) {
        s8[7] = v;
        #pragma unroll
        for (int k = 7; k >= 1; --k)
          if (s8[k] < s8[k - 1]) { unsigned int t = s8[k-1]; s8[k-1] = s8[k]; s8[k] = t; }
      }
    }
    #pragma unroll
    for (int k = 0; k < 8; ++k) ps8[row * 65 + sl * 8 + k] = s8[k];
  }
  __syncthreads();

  if (tid < MB) {
    unsigned int s8[8];
    #pragma unroll
    for (int k = 0; k < 8; ++k) s8[k] = 0xFFFFFFFFu;
    const unsigned int* src = &ps8[tid * 65];
    for (int e = 0; e < 64; ++e) {
      unsigned int v = src[e];
      if (v < s8[7]) {
        s8[7] = v;
        #pragma unroll
        for (int k = 7; k >= 1; --k)
          if (s8[k] < s8[k - 1]) { unsigned int t = s8[k-1]; s8[k-1] = s8[k]; s8[k] = t; }
      }
    }
    #pragma unroll
    for (int k = 0; k < 8; ++k) top8i[tid][k] = (int)(s8[k] & 0x7FFu);
  }
  __syncthreads();

  // ---- Phase D: exact fp64 re-score of 8 candidates per row
  {
    int rr = tid >> 3, j = tid & 7;
    int code = top8i[rr][j];
    const float4* wr4 = (const float4*)(W + (size_t)code * DIM);
    const float*  xr  = x + (size_t)b * DIM * 256 + t0 + rr;
    double d0 = 0.0, d1 = 0.0, d2 = 0.0, d3 = 0.0;
    #pragma unroll 4
    for (int d4 = 0; d4 < 128; ++d4) {
      float4 wv = wr4[d4];
      float x0 = xr[(size_t)(d4*4 + 0) * 256];
      float x1 = xr[(size_t)(d4*4 + 1) * 256];
      float x2 = xr[(size_t)(d4*4 + 2) * 256];
      float x3 = xr[(size_t)(d4*4 + 3) * 256];
      d0 = fma((double)x0, (double)wv.x, d0);
      d1 = fma((double)x1, (double)wv.y, d1);
      d2 = fma((double)x2, (double)wv.z, d2);
      d3 = fma((double)x3, (double)wv.w, d3);
    }
    sc8[rr][j] = w2d[code] - 2.0 * ((d0 + d1) + (d2 + d3));
  }
  __syncthreads();

  // ---- final order: sort 8 by (score, index) asc == top_k(-dist) order
  if (tid < MB) {
    double sd[8]; int id_[8];
    #pragma unroll
    for (int k = 0; k < 8; ++k) { sd[k] = sc8[tid][k]; id_[k] = top8i[tid][k]; }
    #pragma unroll
    for (int i = 0; i < 7; ++i)
      #pragma unroll
      for (int jj = 0; jj < 7; ++jj)
        if (jj < 7 - i) {
          bool sw = (sd[jj] > sd[jj+1]) ||
                    (sd[jj] == sd[jj+1] && id_[jj] > id_[jj+1]);
          if (sw) {
            double td = sd[jj]; sd[jj] = sd[jj+1]; sd[jj+1] = td;
            int    tt = id_[jj]; id_[jj] = id_[jj+1]; id_[jj+1] = tt;
          }
        }
    int n = n0 + tid;
    idx3s[tid] = make_int4(id_[0], id_[1], id_[2], 0);
    out[OUT_IDX_OFF + n] = (float)id_[2];
    atomicAdd(&counts[id_[0]], 1);
    atomicAdd(&counts[id_[1]], 1);
    atomicAdd(&counts[id_[2]], 1);
  }
  __syncthreads();

  // ---- Phase E: fused quantize + straight-through + loss
  {
    int rr = tid & 31, g = tid >> 5;       // 8 d-groups of 64 dims
    int4 ii = idx3s[rr];
    const float4* w0 = (const float4*)(W + (size_t)ii.x * DIM);
    const float4* w1 = (const float4*)(W + (size_t)ii.y * DIM);
    const float4* w2 = (const float4*)(W + (size_t)ii.z * DIM);
    const float*  xr = x + (size_t)b * DIM * 256 + t0 + rr;
    float* outq = out + OUT_Q_OFF + (size_t)b * DIM * 256 + t0 + rr;
    float lsum = 0.0f;
    #pragma unroll 4
    for (int d4 = 0; d4 < 16; ++d4) {
      int idx4 = g * 16 + d4;
      float4 a0 = w0[idx4], a1 = w1[idx4], a2 = w2[idx4];
      float qv[4] = { (a0.x + a1.x + a2.x) * (1.0f/3.0f),
                      (a0.y + a1.y + a2.y) * (1.0f/3.0f),
                      (a0.z + a1.z + a2.z) * (1.0f/3.0f),
                      (a0.w + a1.w + a2.w) * (1.0f/3.0f) };
      #pragma unroll
      for (int e = 0; e < 4; ++e) {
        size_t off = (size_t)(idx4 * 4 + e) * 256;
        float xv = xr[off];
        float diff = qv[e] - xv;             // quantized - inp
        outq[off] = xv + diff;               // straight-through value
        lsum += diff * diff;
      }
    }
    for (int o = 32; o > 0; o >>= 1) lsum += __shfl_down(lsum, o);
    if (lane == 0) lred[w] = lsum;
  }
  __syncthreads();
  if (tid == 0)
    atomicAdd(loss_acc, (lred[0] + lred[1]) + (lred[2] + lred[3]));
}

// ---------------- k_final: loss + perplexity
__global__ __launch_bounds__(256) void k_final(
    const int* __restrict__ counts, const float* __restrict__ loss_acc,
    float* __restrict__ out)
{
  int tid = threadIdx.x;
  float ent = 0.0f;
  for (int k = tid; k < KC; k += 256) {
    float p = (float)counts[k] * (1.0f / 16384.0f);
    ent += p * logf(p + 1e-10f);
  }
  for (int o = 32; o > 0; o >>= 1) ent += __shfl_down(ent, o);
  __shared__ float ps[4];
  if ((tid & 63) == 0) ps[tid >> 6] = ent;
  __syncthreads();
  if (tid == 0) {
    float total = (ps[0] + ps[1]) + (ps[2] + ps[3]);
    out[0] = 1.25f * loss_acc[0] * (1.0f / 8388608.0f);  // q + 0.25*e latent
    out[OUT_P_OFF] = expf(-total);
  }
}

extern "C" void kernel_launch(void* const* d_in, const int* in_sizes, int n_in,
                              void* d_out, int out_size, void* d_ws, size_t ws_size,
                              hipStream_t stream) {
  const float* x = (const float*)d_in[0];
  const float* W = (const float*)d_in[1];
  float* out = (float*)d_out;
  char* ws = (char*)d_ws;
  int*            counts   = (int*)(ws + WS_COUNTS);
  float*          loss_acc = (float*)(ws + WS_LOSS);
  double*         w2d      = (double*)(ws + WS_W2D);
  float*          w2f      = (float*)(ws + WS_W2F);
  unsigned short* Wb       = (unsigned short*)(ws + WS_WB);

  k_prep<<<1024, 256, 0, stream>>>(W, w2d, w2f, Wb, counts, loss_acc);
  k_main<<<NROWS / MB, 256, 0, stream>>>(x, W, Wb, w2f, w2d, counts, out, loss_acc);
  k_final<<<1, 256, 0, stream>>>(counts, loss_acc, out);
}

// Round 7
// 211.970 us; speedup vs baseline: 1.1506x; 1.1506x over previous
//
#include <hip/hip_runtime.h>
#include <math.h>

typedef short  short8  __attribute__((ext_vector_type(8)));
typedef float  floatx4 __attribute__((ext_vector_type(4)));

#define NROWS 16384
#define KC    2048
#define DIM   512
#define MB    32      // rows per k_main block

// d_out element offsets (all float32): loss, q[8388608], perplexity, idx[16384]
#define OUT_Q_OFF    1
#define OUT_P_OFF    (1 + 8388608)
#define OUT_IDX_OFF  (1 + 8388608 + 1)

// ws byte offsets
#define WS_COUNTS 0        // int[2048]   (zeroed in k_prep)
#define WS_LOSS   8192     // float       (zeroed in k_prep)
#define WS_W2D    8448     // double[2048]
#define WS_W2F    24832    // float[2048]
#define WS_WB     33024    // ushort[2048*512] bf16 codebook, FRAGMENT-ORDERED (2 MB)

__device__ __forceinline__ unsigned short f2bf(float f) {
  union { float f; unsigned int u; } v; v.f = f;
  unsigned int u = v.u;
  return (unsigned short)((u + 0x7fffu + ((u >> 16) & 1u)) >> 16);
}

// monotone pack: fp32 score -> ascending uint, low 11 bits replaced by code
__device__ __forceinline__ unsigned int packsc(float s, int code) {
  union { float f; unsigned int u; } v; v.f = s;
  unsigned int u = v.u;
  u = (u & 0x80000000u) ? ~u : (u | 0x80000000u);
  return (u & 0xFFFFF800u) | (unsigned int)code;
}

__device__ __forceinline__ void ins3(unsigned int* t, unsigned int v) {
  if (v < t[2]) {
    t[2] = v;
    if (t[2] < t[1]) { unsigned int tmp = t[1]; t[1] = t[2]; t[2] = tmp; }
    if (t[1] < t[0]) { unsigned int tmp = t[0]; t[0] = t[1]; t[1] = tmp; }
  }
}

// ---------------- k_prep: fused (counts/loss zero) + ||W||^2 + W-reorder
// blocks [0,512):    ||W_k||^2 fp64+fp32, 4 codes per block (+ counts zeroing on blocks 0..8)
// blocks [512,1024): W -> bf16 fragment-ordered Wb (4 fragments per block)
__global__ __launch_bounds__(256) void k_prep(
    const float* __restrict__ W,
    double* __restrict__ w2d, float* __restrict__ w2f,
    unsigned short* __restrict__ Wb,
    int* __restrict__ counts, float* __restrict__ loss_acc)
{
  const int bid = blockIdx.x;
  const int tid = threadIdx.x;

  if (bid < 512) {
    if (bid < 8) counts[bid * 256 + tid] = 0;
    if (bid == 8 && tid == 0) *loss_acc = 0.0f;

    int wave = tid >> 6;
    int lane = tid & 63;
    int k = bid * 4 + wave;
    const float4* row = (const float4*)(W + (size_t)k * DIM);
    float4 a = row[lane];
    float4 b = row[lane + 64];
    double acc = 0.0;
    acc += (double)a.x*a.x + (double)a.y*a.y + (double)a.z*a.z + (double)a.w*a.w;
    acc += (double)b.x*b.x + (double)b.y*b.y + (double)b.z*b.z + (double)b.w*b.w;
    for (int o = 32; o > 0; o >>= 1) acc += __shfl_down(acc, o);
    if (lane == 0) { w2d[k] = acc; w2f[k] = (float)acc; }
  } else {
    int gid  = (bid - 512) * 256 + tid;           // 131072 total
    int lane = gid & 63;
    int f    = gid >> 6;                           // 0..2047
    int c16  = f >> 4, ks = f & 15;
    int l15  = lane & 15, q = lane >> 4;
    const float* src = W + (size_t)(c16 * 16 + l15) * DIM + ks * 32 + q * 8;
    float4 a = *(const float4*)src;
    float4 b = *(const float4*)(src + 4);
    short8 v;
    v[0] = (short)f2bf(a.x); v[1] = (short)f2bf(a.y);
    v[2] = (short)f2bf(a.z); v[3] = (short)f2bf(a.w);
    v[4] = (short)f2bf(b.x); v[5] = (short)f2bf(b.y);
    v[6] = (short)f2bf(b.z); v[7] = (short)f2bf(b.w);
    *(short8*)(Wb + (size_t)f * 512 + lane * 8) = v;
  }
}

// ---------------- k_main: EXACT R0 structure (measured 142us) except Phase B's
// per-block stream rotation. Structure lessons (measured):
//  - D/E stay fused (R2: standalone D/E ~100us exposed vs ~20us fused).
//  - Phase A stays direct per-lane strided loads (R1/R3: staging costs +25us).
//  - Waves keep contiguous disjoint 512KB streams (R5: interleave +27us).
//  - Ring depth is a dead knob (R6: 16-deep == 8-deep).
//  - NEW: rotate each block's tile order by (blockIdx&31)*16 fragments with
//    wrap, decorrelating the machine-wide same-address L2 hotspot (all blocks
//    previously swept the same 16KB window in lockstep at 8.1 of ~34 TB/s).
__global__ __launch_bounds__(256, 2) void k_main(
    const float* __restrict__ x, const float* __restrict__ W,
    const unsigned short* __restrict__ Wb,
    const float* __restrict__ w2f, const double* __restrict__ w2d,
    int* __restrict__ counts, float* __restrict__ out,
    float* __restrict__ loss_acc)
{
  __shared__ unsigned int candU[MB * 192];   // 24 KB packed candidates
  __shared__ unsigned int ps8[MB][8][8];     // 8 KB partial top-8
  __shared__ int    top8i[MB][8];
  __shared__ double sc8[MB][8];
  __shared__ int4   idx3s[MB];
  __shared__ float  lred[4];

  const int tid  = threadIdx.x;
  const int w    = tid >> 6;          // wave id: owns codes [w*512, w*512+512)
  const int lane = tid & 63;
  const int q    = lane >> 4;
  const int l15  = lane & 15;
  const int n0   = blockIdx.x * MB;
  const int b    = n0 >> 8;
  const int t0   = n0 & 255;

  // ---- Phase A: 32 rows -> bf16 A-fragments in registers (2 rowsets x 16 ksteps)
  short8 af[2][16];
  {
    const float* x0 = x + (size_t)b * DIM * 256 + t0 + l15;
    #pragma unroll
    for (int rs = 0; rs < 2; ++rs)
      #pragma unroll
      for (int s = 0; s < 16; ++s) {
        short8 v;
        #pragma unroll
        for (int j = 0; j < 8; ++j) {
          int d = s * 32 + q * 8 + j;
          v[j] = (short)f2bf(x0[(size_t)d * 256 + rs * 16]);
        }
        af[rs][s] = v;
      }
  }

  unsigned int ts[2][4][3];   // packed top-3 per (rowset, acc-reg)
  #pragma unroll
  for (int rs = 0; rs < 2; ++rs)
    #pragma unroll
    for (int i = 0; i < 4; ++i)
      #pragma unroll
      for (int j = 0; j < 3; ++j) ts[rs][i][j] = 0xFFFFFFFFu;

  // ---- Phase B: barrier-free GEMM. Each wave streams its 512 KB of
  //      fragment-ordered Wb through an 8-deep register ring, starting at a
  //      per-block rotated offset (wrap at the wave's 512-fragment boundary).
  //      Fragment consumed at linear step it is (it + r0) & 511; tile cti
  //      covers local 16-code tile ct = (cti + r0/16) & 31, so the code index
  //      stays exactly tied to the fragments being multiplied.
  {
    const unsigned short* base = Wb + (size_t)(w * 512) * 512 + lane * 8;
    const int r0 = (blockIdx.x & 31) << 4;     // rotation, multiple of 16
    short8 ring[8];
    #pragma unroll
    for (int p = 0; p < 8; ++p)
      ring[p] = *(const short8*)(base + (size_t)((r0 + p) & 511) * 512);

    for (int cti = 0; cti < 32; ++cti) {
      floatx4 acc0 = {0.f, 0.f, 0.f, 0.f};
      floatx4 acc1 = {0.f, 0.f, 0.f, 0.f};
      #pragma unroll
      for (int ks = 0; ks < 16; ++ks) {
        int it = cti * 16 + ks;
        int gf = (it + 8 + r0) & 511;          // wrap: always valid data
        short8 bfr = ring[ks & 7];
        ring[ks & 7] = *(const short8*)(base + (size_t)gf * 512);
        acc0 = __builtin_amdgcn_mfma_f32_16x16x32_bf16(af[0][ks], bfr, acc0, 0, 0, 0);
        acc1 = __builtin_amdgcn_mfma_f32_16x16x32_bf16(af[1][ks], bfr, acc1, 0, 0, 0);
      }
      int ct = (cti + (r0 >> 4)) & 31;
      int code = (w * 32 + ct) * 16 + l15;
      float w2 = w2f[code];
      #pragma unroll
      for (int i = 0; i < 4; ++i) {
        ins3(ts[0][i], packsc(fmaf(-2.0f, acc0[i], w2), code));
        ins3(ts[1][i], packsc(fmaf(-2.0f, acc1[i], w2), code));
      }
    }
  }

  // ---- Phase C: dump packed candidates, two-stage merge -> top-8 per row
  #pragma unroll
  for (int rs = 0; rs < 2; ++rs)
    #pragma unroll
    for (int i = 0; i < 4; ++i) {
      int row = rs * 16 + q * 4 + i;
      #pragma unroll
      for (int j = 0; j < 3; ++j)
        candU[row * 192 + w * 48 + l15 * 3 + j] = ts[rs][i][j];
    }
  __syncthreads();

  {
    int row = tid >> 3, sl = tid & 7;
    unsigned int s8[8];
    #pragma unroll
    for (int k = 0; k < 8; ++k) s8[k] = 0xFFFFFFFFu;
    for (int e = 0; e < 24; ++e) {
      unsigned int v = candU[row * 192 + sl * 24 + e];
      if (v < s8[7]) {
        s8[7] = v;
        #pragma unroll
        for (int k = 7; k >= 1; --k)
          if (s8[k] < s8[k - 1]) { unsigned int t = s8[k-1]; s8[k-1] = s8[k]; s8[k] = t; }
      }
    }
    #pragma unroll
    for (int k = 0; k < 8; ++k) ps8[row][sl][k] = s8[k];
  }
  __syncthreads();

  if (tid < MB) {
    unsigned int s8[8];
    #pragma unroll
    for (int k = 0; k < 8; ++k) s8[k] = 0xFFFFFFFFu;
    const unsigned int* src = &ps8[tid][0][0];
    for (int e = 0; e < 64; ++e) {
      unsigned int v = src[e];
      if (v < s8[7]) {
        s8[7] = v;
        #pragma unroll
        for (int k = 7; k >= 1; --k)
          if (s8[k] < s8[k - 1]) { unsigned int t = s8[k-1]; s8[k-1] = s8[k]; s8[k] = t; }
      }
    }
    #pragma unroll
    for (int k = 0; k < 8; ++k) top8i[tid][k] = (int)(s8[k] & 0x7FFu);
  }
  __syncthreads();

  // ---- Phase D: exact fp64 re-score of 8 candidates per row
  {
    int rr = tid >> 3, j = tid & 7;
    int code = top8i[rr][j];
    const float4* wr4 = (const float4*)(W + (size_t)code * DIM);
    const float*  xr  = x + (size_t)b * DIM * 256 + t0 + rr;
    double d0 = 0.0, d1 = 0.0, d2 = 0.0, d3 = 0.0;
    for (int d4 = 0; d4 < 128; ++d4) {
      float4 wv = wr4[d4];
      float x0 = xr[(size_t)(d4*4 + 0) * 256];
      float x1 = xr[(size_t)(d4*4 + 1) * 256];
      float x2 = xr[(size_t)(d4*4 + 2) * 256];
      float x3 = xr[(size_t)(d4*4 + 3) * 256];
      d0 = fma((double)x0, (double)wv.x, d0);
      d1 = fma((double)x1, (double)wv.y, d1);
      d2 = fma((double)x2, (double)wv.z, d2);
      d3 = fma((double)x3, (double)wv.w, d3);
    }
    sc8[rr][j] = w2d[code] - 2.0 * ((d0 + d1) + (d2 + d3));
  }
  __syncthreads();

  // ---- final order: sort 8 by (score, index) asc == top_k(-dist) order
  if (tid < MB) {
    double sd[8]; int id_[8];
    #pragma unroll
    for (int k = 0; k < 8; ++k) { sd[k] = sc8[tid][k]; id_[k] = top8i[tid][k]; }
    #pragma unroll
    for (int i = 0; i < 7; ++i)
      #pragma unroll
      for (int jj = 0; jj < 7; ++jj)
        if (jj < 7 - i) {
          bool sw = (sd[jj] > sd[jj+1]) ||
                    (sd[jj] == sd[jj+1] && id_[jj] > id_[jj+1]);
          if (sw) {
            double td = sd[jj]; sd[jj] = sd[jj+1]; sd[jj+1] = td;
            int    tt = id_[jj]; id_[jj] = id_[jj+1]; id_[jj+1] = tt;
          }
        }
    int n = n0 + tid;
    idx3s[tid] = make_int4(id_[0], id_[1], id_[2], 0);
    out[OUT_IDX_OFF + n] = (float)id_[2];
    atomicAdd(&counts[id_[0]], 1);
    atomicAdd(&counts[id_[1]], 1);
    atomicAdd(&counts[id_[2]], 1);
  }
  __syncthreads();

  // ---- Phase E: fused quantize + straight-through + loss
  {
    int rr = tid & 31, g = tid >> 5;       // 8 d-groups of 64 dims
    int4 ii = idx3s[rr];
    const float4* w0 = (const float4*)(W + (size_t)ii.x * DIM);
    const float4* w1 = (const float4*)(W + (size_t)ii.y * DIM);
    const float4* w2 = (const float4*)(W + (size_t)ii.z * DIM);
    const float*  xr = x + (size_t)b * DIM * 256 + t0 + rr;
    float* outq = out + OUT_Q_OFF + (size_t)b * DIM * 256 + t0 + rr;
    float lsum = 0.0f;
    #pragma unroll 4
    for (int d4 = 0; d4 < 16; ++d4) {
      int idx4 = g * 16 + d4;
      float4 a0 = w0[idx4], a1 = w1[idx4], a2 = w2[idx4];
      float qv[4] = { (a0.x + a1.x + a2.x) * (1.0f/3.0f),
                      (a0.y + a1.y + a2.y) * (1.0f/3.0f),
                      (a0.z + a1.z + a2.z) * (1.0f/3.0f),
                      (a0.w + a1.w + a2.w) * (1.0f/3.0f) };
      #pragma unroll
      for (int e = 0; e < 4; ++e) {
        size_t off = (size_t)(idx4 * 4 + e) * 256;
        float xv = xr[off];
        float diff = qv[e] - xv;             // quantized - inp
        outq[off] = xv + diff;               // straight-through value
        lsum += diff * diff;
      }
    }
    for (int o = 32; o > 0; o >>= 1) lsum += __shfl_down(lsum, o);
    if (lane == 0) lred[w] = lsum;
  }
  __syncthreads();
  if (tid == 0)
    atomicAdd(loss_acc, (lred[0] + lred[1]) + (lred[2] + lred[3]));
}

// ---------------- k_final: loss + perplexity
__global__ __launch_bounds__(256) void k_final(
    const int* __restrict__ counts, const float* __restrict__ loss_acc,
    float* __restrict__ out)
{
  int tid = threadIdx.x;
  float ent = 0.0f;
  for (int k = tid; k < KC; k += 256) {
    float p = (float)counts[k] * (1.0f / 16384.0f);
    ent += p * logf(p + 1e-10f);
  }
  for (int o = 32; o > 0; o >>= 1) ent += __shfl_down(ent, o);
  __shared__ float ps[4];
  if ((tid & 63) == 0) ps[tid >> 6] = ent;
  __syncthreads();
  if (tid == 0) {
    float total = (ps[0] + ps[1]) + (ps[2] + ps[3]);
    out[0] = 1.25f * loss_acc[0] * (1.0f / 8388608.0f);  // q + 0.25*e latent
    out[OUT_P_OFF] = expf(-total);
  }
}

extern "C" void kernel_launch(void* const* d_in, const int* in_sizes, int n_in,
                              void* d_out, int out_size, void* d_ws, size_t ws_size,
                              hipStream_t stream) {
  const float* x = (const float*)d_in[0];
  const float* W = (const float*)d_in[1];
  float* out = (float*)d_out;
  char* ws = (char*)d_ws;
  int*            counts   = (int*)(ws + WS_COUNTS);
  float*          loss_acc = (float*)(ws + WS_LOSS);
  double*         w2d      = (double*)(ws + WS_W2D);
  float*          w2f      = (float*)(ws + WS_W2F);
  unsigned short* Wb       = (unsigned short*)(ws + WS_WB);

  k_prep<<<1024, 256, 0, stream>>>(W, w2d, w2f, Wb, counts, loss_acc);
  k_main<<<NROWS / MB, 256, 0, stream>>>(x, W, Wb, w2f, w2d, counts, out, loss_acc);
  k_final<<<1, 256, 0, stream>>>(counts, loss_acc, out);
}